// Round 15
// baseline (120.808 us; speedup 1.0000x reference)
//
#include <hip/hip_runtime.h>
#include <hip/hip_bf16.h>

typedef float f4 __attribute__((ext_vector_type(4)));
typedef float f32x4 __attribute__((ext_vector_type(4)));
typedef short bf16x8 __attribute__((ext_vector_type(8)));

#define D 128
#define SLOTS 64   // fixed bucket/node; Poisson(6): P(deg>64) ~ 1e-44

// float -> bf16 round-to-nearest-even (finite inputs)
__device__ __forceinline__ unsigned f2bf_u(float f) {
    unsigned u = __builtin_bit_cast(unsigned, f);
    unsigned r = 0x7FFFu + ((u >> 16) & 1u);
    return (u + r) >> 16;
}
__device__ __forceinline__ float bf2f(short s) {
    unsigned u = ((unsigned)(unsigned short)s) << 16;
    return __builtin_bit_cast(float, u);
}

// ---------------------------------------------------------------------------
// Init: x f32 -> bf16 (streaming), W f32 -> bf16, deg = 0.
// ---------------------------------------------------------------------------
__global__ __launch_bounds__(256) void init_kernel(
    const float* __restrict__ x, const float* __restrict__ W,
    unsigned short* __restrict__ xbf, unsigned short* __restrict__ Wbf,
    int* __restrict__ deg, int N)
{
    const int i = blockIdx.x * 256 + threadIdx.x;

    const int nchunk = N * D / 8;          // 1.6M (grid covers in one pass)
    if (i < nchunk) {
        f4 a = reinterpret_cast<const f4*>(x)[i * 2];
        f4 c = reinterpret_cast<const f4*>(x)[i * 2 + 1];
        uint4 o;
        o.x = f2bf_u(a[0]) | (f2bf_u(a[1]) << 16);
        o.y = f2bf_u(a[2]) | (f2bf_u(a[3]) << 16);
        o.z = f2bf_u(c[0]) | (f2bf_u(c[1]) << 16);
        o.w = f2bf_u(c[2]) | (f2bf_u(c[3]) << 16);
        reinterpret_cast<uint4*>(xbf)[i] = o;
    }

    if (i < D * D / 8) {
        f4 a = reinterpret_cast<const f4*>(W)[i * 2];
        f4 c = reinterpret_cast<const f4*>(W)[i * 2 + 1];
        uint4 o;
        o.x = f2bf_u(a[0]) | (f2bf_u(a[1]) << 16);
        o.y = f2bf_u(a[2]) | (f2bf_u(a[3]) << 16);
        o.z = f2bf_u(c[0]) | (f2bf_u(c[1]) << 16);
        o.w = f2bf_u(c[2]) | (f2bf_u(c[3]) << 16);
        reinterpret_cast<uint4*>(Wbf)[i] = o;
    }

    if (i < N) deg[i] = 0;
}

// ---------------------------------------------------------------------------
// GEMM v9: STANDALONE DIAGNOSTIC. One 16-row tile per 256-thread block,
// straight-line (no loop), plain launch_bounds(256) -> compiler free to
// use up to 256 VGPR (NO spill; R12/R13 standalone runs were 32-VGPR
// spilled). Col-split: wave w owns ct {2w,2w+1}. bf16 in/out, zero
// conversions in kernel.
// Fragment maps (m89, swapped operands: D = mfma(A=W, B=x)):
//   A: lane holds W[16ct + (lane&15)][kf*32 + (lane>>4)*8 + e]
//   B: lane holds x[tile*16 + (lane&15)][kf*32 + (lane>>4)*8 + e]
//   D: col = lane&15 -> x-row; row = (lane>>4)*4 + r -> outcol
// => lane owns 4 consecutive output cols of one row -> packed dwordx2 store.
// ---------------------------------------------------------------------------
__global__ __launch_bounds__(256) void gemm_mfma(
    const unsigned short* __restrict__ xbf, const unsigned short* __restrict__ Wbf,
    const float* __restrict__ b, unsigned short* __restrict__ ybf, int N)
{
    const int lane = threadIdx.x & 63;
    const int r16  = lane & 15;
    const int g4   = lane >> 4;              // 0..3
    const int ct0  = (threadIdx.x >> 6) * 2; // wave's first ct block (0,2,4,6)

    const int arow = blockIdx.x * 16 + r16;
    const int srow = (arow < N) ? arow : 0;

    // issue x loads first (4 independent b128), then W loads (8, L2-hot)
    const unsigned short* xr = xbf + (size_t)srow * D + g4 * 8;
    bf16x8 afrag[4];
#pragma unroll
    for (int kf = 0; kf < 4; ++kf)
        afrag[kf] = *reinterpret_cast<const bf16x8*>(xr + kf * 32);

    bf16x8 wfrag[2][4];
#pragma unroll
    for (int c = 0; c < 2; ++c)
#pragma unroll
        for (int kf = 0; kf < 4; ++kf)
            wfrag[c][kf] = *reinterpret_cast<const bf16x8*>(
                Wbf + (size_t)(16 * (ct0 + c) + r16) * D + kf * 32 + g4 * 8);

    f4 bias[2];
#pragma unroll
    for (int c = 0; c < 2; ++c)
        bias[c] = *reinterpret_cast<const f4*>(b + 16 * (ct0 + c) + g4 * 4);

    f32x4 acc0 = {0.f, 0.f, 0.f, 0.f};
    f32x4 acc1 = {0.f, 0.f, 0.f, 0.f};
#pragma unroll
    for (int kf = 0; kf < 4; ++kf) {
        acc0 = __builtin_amdgcn_mfma_f32_16x16x32_bf16(
            wfrag[0][kf], afrag[kf], acc0, 0, 0, 0);
        acc1 = __builtin_amdgcn_mfma_f32_16x16x32_bf16(
            wfrag[1][kf], afrag[kf], acc1, 0, 0, 0);
    }

    if (arow < N) {
        unsigned short* yrow = ybf + (size_t)arow * D + g4 * 4;
        uint2 o0, o1;
        o0.x = f2bf_u(fmaxf(acc0[0] + bias[0][0], 0.f))
             | (f2bf_u(fmaxf(acc0[1] + bias[0][1], 0.f)) << 16);
        o0.y = f2bf_u(fmaxf(acc0[2] + bias[0][2], 0.f))
             | (f2bf_u(fmaxf(acc0[3] + bias[0][3], 0.f)) << 16);
        o1.x = f2bf_u(fmaxf(acc1[0] + bias[1][0], 0.f))
             | (f2bf_u(fmaxf(acc1[1] + bias[1][1], 0.f)) << 16);
        o1.y = f2bf_u(fmaxf(acc1[2] + bias[1][2], 0.f))
             | (f2bf_u(fmaxf(acc1[3] + bias[1][3], 0.f)) << 16);
        *reinterpret_cast<uint2*>(yrow + 16 * ct0)       = o0;
        *reinterpret_cast<uint2*>(yrow + 16 * (ct0 + 1)) = o1;
    }
}

// ---------------------------------------------------------------------------
// Scatter v2: 4 edges per thread — coalesced int4 loads of src/tgt, then 4
// INDEPENDENT atomicAdd->store chains (4x MLP vs serial-per-edge).
// ---------------------------------------------------------------------------
__global__ __launch_bounds__(256) void scatter_hist_kernel(
    const int* __restrict__ src, const int* __restrict__ tgt,
    int* __restrict__ deg, int* __restrict__ slot, int E)
{
    const int t = blockIdx.x * 256 + threadIdx.x;
    const int e0 = t * 4;
    if (e0 + 3 < E) {
        int4 s4 = *reinterpret_cast<const int4*>(src + e0);
        int4 t4 = *reinterpret_cast<const int4*>(tgt + e0);
        int p0 = atomicAdd(&deg[s4.x], 1);
        int p1 = atomicAdd(&deg[s4.y], 1);
        int p2 = atomicAdd(&deg[s4.z], 1);
        int p3 = atomicAdd(&deg[s4.w], 1);
        slot[(size_t)s4.x * SLOTS + p0] = t4.x;
        slot[(size_t)s4.y * SLOTS + p1] = t4.y;
        slot[(size_t)s4.z * SLOTS + p2] = t4.z;
        slot[(size_t)s4.w * SLOTS + p3] = t4.w;
    } else if (e0 < E) {
        for (int e = e0; e < E; ++e) {
            int s = src[e];
            int p = atomicAdd(&deg[s], 1);
            slot[(size_t)s * SLOTS + p] = tgt[e];
        }
    }
}

// ---------------------------------------------------------------------------
// Aggregate: one node per 16-LANE GROUP (16 nodes / 256-thread block).
// Lane c owns columns c*8..c*8+7 (bf16x8 = 16B). Edge loop unrolled 4-wide
// into 4 independent acc chains; edge indices from one int4 broadcast load.
// Gathers predicated on j+u < d (never dereference garbage slot entries).
// ---------------------------------------------------------------------------
__global__ __launch_bounds__(256) void aggregate_bf16(
    const int* __restrict__ deg, const int* __restrict__ slot,
    const unsigned short* __restrict__ ybf, float* __restrict__ out, int N)
{
    const int g  = threadIdx.x >> 4;      // group 0..15
    const int c8 = (threadIdx.x & 15) * 8;

    const int n = blockIdx.x * 16 + g;
    if (n >= N) return;
    const int d = deg[n];
    const int* sl = slot + (size_t)n * SLOTS;

    float a0[8] = {0,0,0,0,0,0,0,0}, a1[8] = {0,0,0,0,0,0,0,0};
    float a2[8] = {0,0,0,0,0,0,0,0}, a3[8] = {0,0,0,0,0,0,0,0};

    for (int j = 0; j < d; j += 4) {
        int4 tq = *reinterpret_cast<const int4*>(sl + j);   // 16B-aligned bucket
        if (j + 0 < d) {
            bf16x8 v = *reinterpret_cast<const bf16x8*>(ybf + (size_t)tq.x * D + c8);
#pragma unroll
            for (int e = 0; e < 8; ++e) a0[e] += bf2f(v[e]);
        }
        if (j + 1 < d) {
            bf16x8 v = *reinterpret_cast<const bf16x8*>(ybf + (size_t)tq.y * D + c8);
#pragma unroll
            for (int e = 0; e < 8; ++e) a1[e] += bf2f(v[e]);
        }
        if (j + 2 < d) {
            bf16x8 v = *reinterpret_cast<const bf16x8*>(ybf + (size_t)tq.z * D + c8);
#pragma unroll
            for (int e = 0; e < 8; ++e) a2[e] += bf2f(v[e]);
        }
        if (j + 3 < d) {
            bf16x8 v = *reinterpret_cast<const bf16x8*>(ybf + (size_t)tq.w * D + c8);
#pragma unroll
            for (int e = 0; e < 8; ++e) a3[e] += bf2f(v[e]);
        }
    }

    const float dinv = 1.0f / fmaxf((float)d, 1.f);
    f4 o0, o1;
#pragma unroll
    for (int e = 0; e < 4; ++e)
        o0[e] = ((a0[e] + a1[e]) + (a2[e] + a3[e])) * dinv;
#pragma unroll
    for (int e = 4; e < 8; ++e)
        o1[e - 4] = ((a0[e] + a1[e]) + (a2[e] + a3[e])) * dinv;

    float* orow = out + (size_t)n * D + c8;
    *reinterpret_cast<f4*>(orow)     = o0;
    *reinterpret_cast<f4*>(orow + 4) = o1;
}

extern "C" void kernel_launch(void* const* d_in, const int* in_sizes, int n_in,
                              void* d_out, int out_size, void* d_ws, size_t ws_size,
                              hipStream_t stream) {
    const float* x  = (const float*)d_in[0];
    const int*   ei = (const int*)d_in[1];     // [2, E] row-major int32
    const float* W  = (const float*)d_in[2];
    const float* b  = (const float*)d_in[3];
    float* out = (float*)d_out;

    const int N = in_sizes[0] / D;             // 100000
    const int E = in_sizes[1] / 2;             // 600000
    const int* src = ei;
    const int* tgt = ei + E;

    // Workspace: xbf (25.6MB) | ybf (25.6MB) | Wbf (32KB) | deg (400KB) | slot (25.6MB)
    char* ws = (char*)d_ws;
    unsigned short* xbf = (unsigned short*)ws;   ws += (size_t)N * D * sizeof(unsigned short);
    unsigned short* ybf = (unsigned short*)ws;   ws += (size_t)N * D * sizeof(unsigned short);
    unsigned short* Wbf = (unsigned short*)ws;   ws += (size_t)D * D * sizeof(unsigned short);
    int* deg  = (int*)ws;                        ws += (size_t)N * sizeof(int);
    int* slot = (int*)ws;                        ws += (size_t)N * SLOTS * sizeof(int);

    // 0) x -> bf16, W -> bf16, deg = 0 (streaming)
    int ib = (N * D / 8 + 255) / 256;                         // 6250
    init_kernel<<<ib, 256, 0, stream>>>(x, W, xbf, Wbf, deg, N);

    // 1) GEMM standalone (1 tile/block, straight-line, no spill)
    int ntiles = (N + 15) / 16;                               // 6250
    gemm_mfma<<<ntiles, 256, 0, stream>>>(xbf, Wbf, b, ybf, N);

    // 2) scatter (4 edges/thread, 4x MLP)
    int sb = (E / 4 + 255) / 256;                             // 586
    scatter_hist_kernel<<<sb, 256, 0, stream>>>(src, tgt, deg, slot, E);

    // 3) gather-aggregate + normalize (1 node per 16-lane group)
    int ab = (N + 15) / 16;                                   // 6250
    aggregate_bf16<<<ab, 256, 0, stream>>>(deg, slot, ybf, out, N);
}

// Round 16
// 103.452 us; speedup vs baseline: 1.1678x; 1.1678x over previous
//
#include <hip/hip_runtime.h>
#include <hip/hip_bf16.h>

typedef float f4 __attribute__((ext_vector_type(4)));
typedef float f32x4 __attribute__((ext_vector_type(4)));
typedef short bf16x8 __attribute__((ext_vector_type(8)));

#define D 128
#define SLOTS 64   // fixed bucket/node; Poisson(6): P(deg>64) ~ 1e-44

// float -> bf16 round-to-nearest-even (finite inputs)
__device__ __forceinline__ unsigned f2bf_u(float f) {
    unsigned u = __builtin_bit_cast(unsigned, f);
    unsigned r = 0x7FFFu + ((u >> 16) & 1u);
    return (u + r) >> 16;
}
__device__ __forceinline__ float bf2f(short s) {
    unsigned u = ((unsigned)(unsigned short)s) << 16;
    return __builtin_bit_cast(float, u);
}

// ---------------------------------------------------------------------------
// Init: x f32 -> bf16 (streaming), W f32 -> bf16, deg = 0.
// ---------------------------------------------------------------------------
__global__ __launch_bounds__(256) void init_kernel(
    const float* __restrict__ x, const float* __restrict__ W,
    unsigned short* __restrict__ xbf, unsigned short* __restrict__ Wbf,
    int* __restrict__ deg, int N)
{
    const int i = blockIdx.x * 256 + threadIdx.x;

    const int nchunk = N * D / 8;          // 1.6M (grid covers in one pass)
    if (i < nchunk) {
        f4 a = reinterpret_cast<const f4*>(x)[i * 2];
        f4 c = reinterpret_cast<const f4*>(x)[i * 2 + 1];
        uint4 o;
        o.x = f2bf_u(a[0]) | (f2bf_u(a[1]) << 16);
        o.y = f2bf_u(a[2]) | (f2bf_u(a[3]) << 16);
        o.z = f2bf_u(c[0]) | (f2bf_u(c[1]) << 16);
        o.w = f2bf_u(c[2]) | (f2bf_u(c[3]) << 16);
        reinterpret_cast<uint4*>(xbf)[i] = o;
    }

    if (i < D * D / 8) {
        f4 a = reinterpret_cast<const f4*>(W)[i * 2];
        f4 c = reinterpret_cast<const f4*>(W)[i * 2 + 1];
        uint4 o;
        o.x = f2bf_u(a[0]) | (f2bf_u(a[1]) << 16);
        o.y = f2bf_u(a[2]) | (f2bf_u(a[3]) << 16);
        o.z = f2bf_u(c[0]) | (f2bf_u(c[1]) << 16);
        o.w = f2bf_u(c[2]) | (f2bf_u(c[3]) << 16);
        reinterpret_cast<uint4*>(Wbf)[i] = o;
    }

    if (i < N) deg[i] = 0;
}

// ---------------------------------------------------------------------------
// GEMM + scatter v10: MLP-PINNED. R15 proved the compiler register-minimizes
// (VGPR_Count=24: acc 8 + afrag 16, ZERO regs for wfrag) and serializes ~13
// dependent loads/wave (~22000 cy wave lifetime). Fix: issue ALL loads
// (afrag, wfrag, bias, scatter src/tgt) then __builtin_amdgcn_sched_barrier(0)
// to forbid the scheduler from sinking loads past it -> one overlapped
// latency window. Plain launch_bounds(256): compiler free to hold ~80 VGPR.
// VGPR_Count in the counters is the proof the pin held (expect 64-96).
// Fused scatter tail (single iteration: grid*256 = 1.6M >= E).
// Fragment maps (m89, swapped operands: D = mfma(A=W, B=x)):
//   A: lane holds W[16ct + (lane&15)][kf*32 + (lane>>4)*8 + e]
//   B: lane holds x[tile*16 + (lane&15)][kf*32 + (lane>>4)*8 + e]
//   D: col = lane&15 -> x-row; row = (lane>>4)*4 + r -> outcol
// ---------------------------------------------------------------------------
__global__ __launch_bounds__(256) void gemm_scatter(
    const unsigned short* __restrict__ xbf, const unsigned short* __restrict__ Wbf,
    const float* __restrict__ b, unsigned short* __restrict__ ybf,
    const int* __restrict__ src, const int* __restrict__ tgt,
    int* __restrict__ deg, int* __restrict__ slot, int N, int E)
{
    const int lane = threadIdx.x & 63;
    const int r16  = lane & 15;
    const int g4   = lane >> 4;              // 0..3
    const int ct0  = (threadIdx.x >> 6) * 2; // wave's first ct block (0,2,4,6)

    const int arow = blockIdx.x * 16 + r16;
    const int srow = (arow < N) ? arow : 0;

    // ---- issue ALL independent loads ----
    const unsigned short* xr = xbf + (size_t)srow * D + g4 * 8;
    bf16x8 afrag[4];
#pragma unroll
    for (int kf = 0; kf < 4; ++kf)
        afrag[kf] = *reinterpret_cast<const bf16x8*>(xr + kf * 32);

    bf16x8 wfrag[2][4];
#pragma unroll
    for (int c = 0; c < 2; ++c)
#pragma unroll
        for (int kf = 0; kf < 4; ++kf)
            wfrag[c][kf] = *reinterpret_cast<const bf16x8*>(
                Wbf + (size_t)(16 * (ct0 + c) + r16) * D + kf * 32 + g4 * 8);

    f4 bias[2];
#pragma unroll
    for (int c = 0; c < 2; ++c)
        bias[c] = *reinterpret_cast<const f4*>(b + 16 * (ct0 + c) + g4 * 4);

    // scatter operands for this thread's edge (also in the parallel window)
    const int eidx = blockIdx.x * 256 + threadIdx.x;
    int sv = -1, tv = 0;
    if (eidx < E) { sv = src[eidx]; tv = tgt[eidx]; }

    // ---- pin: nothing above may sink below ----
    __builtin_amdgcn_sched_barrier(0);

    f32x4 acc0 = {0.f, 0.f, 0.f, 0.f};
    f32x4 acc1 = {0.f, 0.f, 0.f, 0.f};
#pragma unroll
    for (int kf = 0; kf < 4; ++kf) {
        acc0 = __builtin_amdgcn_mfma_f32_16x16x32_bf16(
            wfrag[0][kf], afrag[kf], acc0, 0, 0, 0);
        acc1 = __builtin_amdgcn_mfma_f32_16x16x32_bf16(
            wfrag[1][kf], afrag[kf], acc1, 0, 0, 0);
    }

    if (arow < N) {
        unsigned short* yrow = ybf + (size_t)arow * D + g4 * 4;
        uint2 o0, o1;
        o0.x = f2bf_u(fmaxf(acc0[0] + bias[0][0], 0.f))
             | (f2bf_u(fmaxf(acc0[1] + bias[0][1], 0.f)) << 16);
        o0.y = f2bf_u(fmaxf(acc0[2] + bias[0][2], 0.f))
             | (f2bf_u(fmaxf(acc0[3] + bias[0][3], 0.f)) << 16);
        o1.x = f2bf_u(fmaxf(acc1[0] + bias[1][0], 0.f))
             | (f2bf_u(fmaxf(acc1[1] + bias[1][1], 0.f)) << 16);
        o1.y = f2bf_u(fmaxf(acc1[2] + bias[1][2], 0.f))
             | (f2bf_u(fmaxf(acc1[3] + bias[1][3], 0.f)) << 16);
        *reinterpret_cast<uint2*>(yrow + 16 * ct0)       = o0;
        *reinterpret_cast<uint2*>(yrow + 16 * (ct0 + 1)) = o1;
    }

    // ---- scatter (operands already loaded above the barrier) ----
    if (sv >= 0) {
        int p = atomicAdd(&deg[sv], 1);
        slot[(size_t)sv * SLOTS + p] = tv;
    }
}

// ---------------------------------------------------------------------------
// Aggregate: one node per 16-LANE GROUP (16 nodes / 256-thread block).
// Lane c owns columns c*8..c*8+7 (bf16x8 = 16B). Edge loop unrolled 4-wide
// into 4 independent acc chains; edge indices from one int4 broadcast load.
// Gathers predicated on j+u < d (never dereference garbage slot entries).
// ---------------------------------------------------------------------------
__global__ __launch_bounds__(256) void aggregate_bf16(
    const int* __restrict__ deg, const int* __restrict__ slot,
    const unsigned short* __restrict__ ybf, float* __restrict__ out, int N)
{
    const int g  = threadIdx.x >> 4;      // group 0..15
    const int c8 = (threadIdx.x & 15) * 8;

    const int n = blockIdx.x * 16 + g;
    if (n >= N) return;
    const int d = deg[n];
    const int* sl = slot + (size_t)n * SLOTS;

    float a0[8] = {0,0,0,0,0,0,0,0}, a1[8] = {0,0,0,0,0,0,0,0};
    float a2[8] = {0,0,0,0,0,0,0,0}, a3[8] = {0,0,0,0,0,0,0,0};

    for (int j = 0; j < d; j += 4) {
        int4 tq = *reinterpret_cast<const int4*>(sl + j);   // 16B-aligned bucket
        if (j + 0 < d) {
            bf16x8 v = *reinterpret_cast<const bf16x8*>(ybf + (size_t)tq.x * D + c8);
#pragma unroll
            for (int e = 0; e < 8; ++e) a0[e] += bf2f(v[e]);
        }
        if (j + 1 < d) {
            bf16x8 v = *reinterpret_cast<const bf16x8*>(ybf + (size_t)tq.y * D + c8);
#pragma unroll
            for (int e = 0; e < 8; ++e) a1[e] += bf2f(v[e]);
        }
        if (j + 2 < d) {
            bf16x8 v = *reinterpret_cast<const bf16x8*>(ybf + (size_t)tq.z * D + c8);
#pragma unroll
            for (int e = 0; e < 8; ++e) a2[e] += bf2f(v[e]);
        }
        if (j + 3 < d) {
            bf16x8 v = *reinterpret_cast<const bf16x8*>(ybf + (size_t)tq.w * D + c8);
#pragma unroll
            for (int e = 0; e < 8; ++e) a3[e] += bf2f(v[e]);
        }
    }

    const float dinv = 1.0f / fmaxf((float)d, 1.f);
    f4 o0, o1;
#pragma unroll
    for (int e = 0; e < 4; ++e)
        o0[e] = ((a0[e] + a1[e]) + (a2[e] + a3[e])) * dinv;
#pragma unroll
    for (int e = 4; e < 8; ++e)
        o1[e - 4] = ((a0[e] + a1[e]) + (a2[e] + a3[e])) * dinv;

    float* orow = out + (size_t)n * D + c8;
    *reinterpret_cast<f4*>(orow)     = o0;
    *reinterpret_cast<f4*>(orow + 4) = o1;
}

extern "C" void kernel_launch(void* const* d_in, const int* in_sizes, int n_in,
                              void* d_out, int out_size, void* d_ws, size_t ws_size,
                              hipStream_t stream) {
    const float* x  = (const float*)d_in[0];
    const int*   ei = (const int*)d_in[1];     // [2, E] row-major int32
    const float* W  = (const float*)d_in[2];
    const float* b  = (const float*)d_in[3];
    float* out = (float*)d_out;

    const int N = in_sizes[0] / D;             // 100000
    const int E = in_sizes[1] / 2;             // 600000
    const int* src = ei;
    const int* tgt = ei + E;

    // Workspace: xbf (25.6MB) | ybf (25.6MB) | Wbf (32KB) | deg (400KB) | slot (25.6MB)
    char* ws = (char*)d_ws;
    unsigned short* xbf = (unsigned short*)ws;   ws += (size_t)N * D * sizeof(unsigned short);
    unsigned short* ybf = (unsigned short*)ws;   ws += (size_t)N * D * sizeof(unsigned short);
    unsigned short* Wbf = (unsigned short*)ws;   ws += (size_t)D * D * sizeof(unsigned short);
    int* deg  = (int*)ws;                        ws += (size_t)N * sizeof(int);
    int* slot = (int*)ws;                        ws += (size_t)N * SLOTS * sizeof(int);

    // 0) x -> bf16, W -> bf16, deg = 0 (streaming)
    int ib = (N * D / 8 + 255) / 256;                         // 6250
    init_kernel<<<ib, 256, 0, stream>>>(x, W, xbf, Wbf, deg, N);

    // 1) GEMM (sched_barrier-pinned loads) + fused scatter (1 edge/thread)
    int ntiles = (N + 15) / 16;                               // 6250 (*256 >= E)
    gemm_scatter<<<ntiles, 256, 0, stream>>>(xbf, Wbf, b, ybf, src, tgt,
                                             deg, slot, N, E);

    // 2) gather-aggregate + normalize (1 node per 16-lane group)
    int ab = (N + 15) / 16;                                   // 6250
    aggregate_bf16<<<ab, 256, 0, stream>>>(deg, slot, ybf, out, N);
}

// Round 17
// 93.177 us; speedup vs baseline: 1.2965x; 1.1103x over previous
//
#include <hip/hip_runtime.h>
#include <hip/hip_bf16.h>

typedef float f4 __attribute__((ext_vector_type(4)));
typedef float f32x4 __attribute__((ext_vector_type(4)));
typedef short bf16x8 __attribute__((ext_vector_type(8)));

#define D 128
#define BM 128     // rows per block tile
#define SLOTS 64   // fixed bucket/node; Poisson(6): P(deg>64) ~ 1e-44

// float -> bf16 round-to-nearest-even (finite inputs)
__device__ __forceinline__ unsigned f2bf_u(float f) {
    unsigned u = __builtin_bit_cast(unsigned, f);
    unsigned r = 0x7FFFu + ((u >> 16) & 1u);
    return (u + r) >> 16;
}
__device__ __forceinline__ float bf2f(short s) {
    unsigned u = ((unsigned)(unsigned short)s) << 16;
    return __builtin_bit_cast(float, u);
}

// ---------------------------------------------------------------------------
// Init: x f32 -> bf16 (streaming), W f32 -> bf16, deg = 0, zero xbf pad rows.
// ---------------------------------------------------------------------------
__global__ __launch_bounds__(256) void init_kernel(
    const float* __restrict__ x, const float* __restrict__ W,
    unsigned short* __restrict__ xbf, unsigned short* __restrict__ Wbf,
    int* __restrict__ deg, int N, int NP)
{
    const int i = blockIdx.x * 256 + threadIdx.x;

    const int nchunk = N * D / 8;          // 1.6M (grid covers in one pass)
    if (i < nchunk) {
        f4 a = reinterpret_cast<const f4*>(x)[i * 2];
        f4 c = reinterpret_cast<const f4*>(x)[i * 2 + 1];
        uint4 o;
        o.x = f2bf_u(a[0]) | (f2bf_u(a[1]) << 16);
        o.y = f2bf_u(a[2]) | (f2bf_u(a[3]) << 16);
        o.z = f2bf_u(c[0]) | (f2bf_u(c[1]) << 16);
        o.w = f2bf_u(c[2]) | (f2bf_u(c[3]) << 16);
        reinterpret_cast<uint4*>(xbf)[i] = o;
    }

    // zero the padded tail rows (so the last gemm block stages clean data)
    const int tailchunks = (NP - N) * D / 8;
    if (i < tailchunks) {
        uint4 z = {0u, 0u, 0u, 0u};
        reinterpret_cast<uint4*>(xbf + (size_t)N * D)[i] = z;
    }

    if (i < D * D / 8) {
        f4 a = reinterpret_cast<const f4*>(W)[i * 2];
        f4 c = reinterpret_cast<const f4*>(W)[i * 2 + 1];
        uint4 o;
        o.x = f2bf_u(a[0]) | (f2bf_u(a[1]) << 16);
        o.y = f2bf_u(a[2]) | (f2bf_u(a[3]) << 16);
        o.z = f2bf_u(c[0]) | (f2bf_u(c[1]) << 16);
        o.w = f2bf_u(c[2]) | (f2bf_u(c[3]) << 16);
        reinterpret_cast<uint4*>(Wbf)[i] = o;
    }

    if (i < N) deg[i] = 0;
}

// ---------------------------------------------------------------------------
// GEMM v11: CANONICAL LDS-STAGED BLOCK GEMM (guide §5) + fused scatter.
// Block = 256 threads (4 waves), tile = BM=128 rows x all 128 cols.
// Stage x-tile (32KB) AND W (32KB) into LDS: coalesced uint4 global reads +
// XOR-swizzled ds_write_b128 (byte ^= (row&7)<<4) so the per-(row-slice)
// ds_read_b128 fragment reads are conflict-free (T2/G4 both-sides recipe).
// This eliminates the per-lane 16-segment global gathers that every prior
// structure shared (5M fragmented L1/L2 transactions) — the one invariant
// across six 40-62us variants.
// Wave w computes rows [w*32, w*32+32): acc[2][8] (64 VGPR), 4 K-steps x
// (2+8 ds_read_b128 + 16 MFMA).
// Fragment maps (m89, swapped operands: D = mfma(A=W, B=x)):
//   A: lane holds W[16ct + (lane&15)][ks*32 + (lane>>4)*8 + e]
//   B: lane holds x[row0 + (lane&15)][ks*32 + (lane>>4)*8 + e]
//   D: col = lane&15 -> x-row; row = (lane>>4)*4 + r -> outcol
// => lane owns 4 consecutive output cols of one row -> packed dwordx2 store.
// Scatter tail: grid-stride over edges (deg zeroed by init).
// ---------------------------------------------------------------------------
__global__ __launch_bounds__(256) void gemm_scatter(
    const unsigned short* __restrict__ xbf, const unsigned short* __restrict__ Wbf,
    const float* __restrict__ b, unsigned short* __restrict__ ybf,
    const int* __restrict__ src, const int* __restrict__ tgt,
    int* __restrict__ deg, int* __restrict__ slot, int N, int E)
{
    __shared__ unsigned short Al[BM * D];   // 32 KB, swizzled
    __shared__ unsigned short Wl[D * D];    // 32 KB, swizzled
    __shared__ float bl[D];

    const int tid  = threadIdx.x;
    const int wave = tid >> 6;
    const int lane = tid & 63;
    const int r16  = lane & 15;
    const int g4   = lane >> 4;

    // ---- stage x-tile and W: coalesced 16B reads, swizzled 16B LDS writes --
    {
        const char* Ag = (const char*)(xbf + (size_t)blockIdx.x * BM * D);
        const char* Wg = (const char*)Wbf;
#pragma unroll
        for (int it = 0; it < 8; ++it) {
            unsigned lo = (unsigned)(it * 4096 + tid * 16);
            unsigned swz = ((lo >> 8) & 7) << 4;
            uint4 va = *reinterpret_cast<const uint4*>(Ag + lo);
            uint4 vw = *reinterpret_cast<const uint4*>(Wg + lo);
            *reinterpret_cast<uint4*>((char*)Al + (lo ^ swz)) = va;
            *reinterpret_cast<uint4*>((char*)Wl + (lo ^ swz)) = vw;
        }
        if (tid < D) bl[tid] = b[tid];
    }
    __syncthreads();

    // ---- compute: 4 K-steps, acc[2 rowtiles][8 coltiles] ----
    f32x4 acc[2][8];
#pragma unroll
    for (int rt = 0; rt < 2; ++rt)
#pragma unroll
        for (int ct = 0; ct < 8; ++ct)
            acc[rt][ct] = (f32x4){0.f, 0.f, 0.f, 0.f};

    const unsigned rswz = (unsigned)((r16 & 7) << 4);
#pragma unroll
    for (int ks = 0; ks < 4; ++ks) {
        const unsigned coff = (unsigned)((ks * 64 + g4 * 16)) ^ rswz;
        bf16x8 xf[2], wf[8];
#pragma unroll
        for (int rt = 0; rt < 2; ++rt) {
            unsigned row = (unsigned)(wave * 32 + rt * 16 + r16);
            xf[rt] = *reinterpret_cast<const bf16x8*>((const char*)Al + row * 256 + coff);
        }
#pragma unroll
        for (int ct = 0; ct < 8; ++ct) {
            unsigned wrow = (unsigned)(ct * 16 + r16);
            wf[ct] = *reinterpret_cast<const bf16x8*>((const char*)Wl + wrow * 256 + coff);
        }
#pragma unroll
        for (int ct = 0; ct < 8; ++ct) {
#pragma unroll
            for (int rt = 0; rt < 2; ++rt)
                acc[rt][ct] = __builtin_amdgcn_mfma_f32_16x16x32_bf16(
                    wf[ct], xf[rt], acc[rt][ct], 0, 0, 0);
        }
    }

    // ---- epilogue: bias + relu + packed bf16 stores ----
#pragma unroll
    for (int rt = 0; rt < 2; ++rt) {
        const int arow = blockIdx.x * BM + wave * 32 + rt * 16 + r16;
        if (arow < N) {
            unsigned short* yrow = ybf + (size_t)arow * D + g4 * 4;
#pragma unroll
            for (int ct = 0; ct < 8; ++ct) {
                f4 bias = *reinterpret_cast<const f4*>(bl + ct * 16 + g4 * 4);
                uint2 o;
                o.x = f2bf_u(fmaxf(acc[rt][ct][0] + bias[0], 0.f))
                    | (f2bf_u(fmaxf(acc[rt][ct][1] + bias[1], 0.f)) << 16);
                o.y = f2bf_u(fmaxf(acc[rt][ct][2] + bias[2], 0.f))
                    | (f2bf_u(fmaxf(acc[rt][ct][3] + bias[3], 0.f)) << 16);
                *reinterpret_cast<uint2*>(yrow + 16 * ct) = o;
            }
        }
    }

    // ---- fused histogram + bucket scatter (grid-stride, 3 edges/thread) ----
    for (int e = blockIdx.x * 256 + tid; e < E; e += gridDim.x * 256) {
        int s = src[e];
        int p = atomicAdd(&deg[s], 1);
        slot[(size_t)s * SLOTS + p] = tgt[e];
    }
}

// ---------------------------------------------------------------------------
// Aggregate: one node per 16-LANE GROUP (16 nodes / 256-thread block).
// Lane c owns columns c*8..c*8+7 (bf16x8 = 16B). Edge loop unrolled 4-wide
// into 4 independent acc chains; edge indices from one int4 broadcast load.
// Gathers predicated on j+u < d (never dereference garbage slot entries).
// ---------------------------------------------------------------------------
__global__ __launch_bounds__(256) void aggregate_bf16(
    const int* __restrict__ deg, const int* __restrict__ slot,
    const unsigned short* __restrict__ ybf, float* __restrict__ out, int N)
{
    const int g  = threadIdx.x >> 4;      // group 0..15
    const int c8 = (threadIdx.x & 15) * 8;

    const int n = blockIdx.x * 16 + g;
    if (n >= N) return;
    const int d = deg[n];
    const int* sl = slot + (size_t)n * SLOTS;

    float a0[8] = {0,0,0,0,0,0,0,0}, a1[8] = {0,0,0,0,0,0,0,0};
    float a2[8] = {0,0,0,0,0,0,0,0}, a3[8] = {0,0,0,0,0,0,0,0};

    for (int j = 0; j < d; j += 4) {
        int4 tq = *reinterpret_cast<const int4*>(sl + j);   // 16B-aligned bucket
        if (j + 0 < d) {
            bf16x8 v = *reinterpret_cast<const bf16x8*>(ybf + (size_t)tq.x * D + c8);
#pragma unroll
            for (int e = 0; e < 8; ++e) a0[e] += bf2f(v[e]);
        }
        if (j + 1 < d) {
            bf16x8 v = *reinterpret_cast<const bf16x8*>(ybf + (size_t)tq.y * D + c8);
#pragma unroll
            for (int e = 0; e < 8; ++e) a1[e] += bf2f(v[e]);
        }
        if (j + 2 < d) {
            bf16x8 v = *reinterpret_cast<const bf16x8*>(ybf + (size_t)tq.z * D + c8);
#pragma unroll
            for (int e = 0; e < 8; ++e) a2[e] += bf2f(v[e]);
        }
        if (j + 3 < d) {
            bf16x8 v = *reinterpret_cast<const bf16x8*>(ybf + (size_t)tq.w * D + c8);
#pragma unroll
            for (int e = 0; e < 8; ++e) a3[e] += bf2f(v[e]);
        }
    }

    const float dinv = 1.0f / fmaxf((float)d, 1.f);
    f4 o0, o1;
#pragma unroll
    for (int e = 0; e < 4; ++e)
        o0[e] = ((a0[e] + a1[e]) + (a2[e] + a3[e])) * dinv;
#pragma unroll
    for (int e = 4; e < 8; ++e)
        o1[e - 4] = ((a0[e] + a1[e]) + (a2[e] + a3[e])) * dinv;

    float* orow = out + (size_t)n * D + c8;
    *reinterpret_cast<f4*>(orow)     = o0;
    *reinterpret_cast<f4*>(orow + 4) = o1;
}

extern "C" void kernel_launch(void* const* d_in, const int* in_sizes, int n_in,
                              void* d_out, int out_size, void* d_ws, size_t ws_size,
                              hipStream_t stream) {
    const float* x  = (const float*)d_in[0];
    const int*   ei = (const int*)d_in[1];     // [2, E] row-major int32
    const float* W  = (const float*)d_in[2];
    const float* b  = (const float*)d_in[3];
    float* out = (float*)d_out;

    const int N = in_sizes[0] / D;             // 100000
    const int E = in_sizes[1] / 2;             // 600000
    const int* src = ei;
    const int* tgt = ei + E;

    const int nblk = (N + BM - 1) / BM;        // 782
    const int NP   = nblk * BM;                // 100096 (padded rows)

    // Workspace: xbf (NP rows) | ybf (NP rows) | Wbf | deg | slot
    char* ws = (char*)d_ws;
    unsigned short* xbf = (unsigned short*)ws;   ws += (size_t)NP * D * sizeof(unsigned short);
    unsigned short* ybf = (unsigned short*)ws;   ws += (size_t)NP * D * sizeof(unsigned short);
    unsigned short* Wbf = (unsigned short*)ws;   ws += (size_t)D * D * sizeof(unsigned short);
    int* deg  = (int*)ws;                        ws += (size_t)N * sizeof(int);
    int* slot = (int*)ws;                        ws += (size_t)N * SLOTS * sizeof(int);

    // 0) x -> bf16 (+ pad zero), W -> bf16, deg = 0
    int ib = (N * D / 8 + 255) / 256;                         // 6250
    init_kernel<<<ib, 256, 0, stream>>>(x, W, xbf, Wbf, deg, N, NP);

    // 1) canonical LDS-staged GEMM + fused edge scatter
    gemm_scatter<<<nblk, 256, 0, stream>>>(xbf, Wbf, b, ybf, src, tgt,
                                           deg, slot, N, E);

    // 2) gather-aggregate + normalize (1 node per 16-lane group)
    int ab = (N + 15) / 16;                                   // 6250
    aggregate_bf16<<<ab, 256, 0, stream>>>(deg, slot, ybf, out, N);
}